// Round 20
// baseline (255.291 us; speedup 1.0000x reference)
//
#include <hip/hip_runtime.h>
#include <hip/hip_bf16.h>

typedef unsigned short u16;
typedef unsigned int u32;
using short8 = __attribute__((ext_vector_type(8))) short;
using f32x4  = __attribute__((ext_vector_type(4))) float;
using f32x16 = __attribute__((ext_vector_type(16))) float;
using u32x2  = __attribute__((ext_vector_type(2))) unsigned int;
using u32x4  = __attribute__((ext_vector_type(4))) unsigned int;

#define B_  4
#define L_  2048
#define S_  2048
#define DM  1024
#define H_  16
#define E_  64

__device__ __forceinline__ u16 f2bf(float f) {
  union { float f; unsigned u; } v; v.f = f;
  unsigned u = v.u;
  unsigned r = (u + 0x7fffu + ((u >> 16) & 1u)) >> 16;  // RNE
  return (u16)r;
}

__device__ __forceinline__ float exp2a(float x) {
  float r; asm("v_exp_f32 %0, %1" : "=v"(r) : "v"(x)); return r;
}

__device__ __forceinline__ u32 cvtpk(float lo, float hi) {
  u32 r; asm("v_cvt_pk_bf16_f32 %0, %1, %2" : "=v"(r) : "v"(lo), "v"(hi));
  return r;
}

__device__ __forceinline__ f32x4 mfma16(short8 a, short8 b, f32x4 c) {
  return __builtin_amdgcn_mfma_f32_16x16x32_bf16(a, b, c, 0, 0, 0);
}

__device__ __forceinline__ f32x16 mfma32(short8 a, short8 b, f32x16 c) {
  return __builtin_amdgcn_mfma_f32_32x32x16_bf16(a, b, c, 0, 0, 0);
}

__device__ __forceinline__ void gload_lds16(const u16* g, u16* l) {
  __builtin_amdgcn_global_load_lds(
      (const __attribute__((address_space(1))) unsigned int*)(const void*)g,
      (__attribute__((address_space(3))) unsigned int*)(void*)l, 16, 0, 0);
}

// ---------------- fused weight transpose+convert (one launch, z=4) ---------
__global__ __launch_bounds__(256) void transp_all(const float* __restrict__ w0,
                                                  const float* __restrict__ w1,
                                                  const float* __restrict__ w2,
                                                  const float* __restrict__ w3,
                                                  u16* __restrict__ t0,
                                                  u16* __restrict__ t1,
                                                  u16* __restrict__ t2,
                                                  u16* __restrict__ t3) {
  const float* W = blockIdx.z == 0 ? w0 : blockIdx.z == 1 ? w1 :
                   blockIdx.z == 2 ? w2 : w3;
  u16* Wt = blockIdx.z == 0 ? t0 : blockIdx.z == 1 ? t1 :
            blockIdx.z == 2 ? t2 : t3;
  __shared__ float t[32][33];
  int tx = threadIdx.x & 31, ty = (threadIdx.x >> 5) & 7;
#pragma unroll
  for (int j = 0; j < 32; j += 8)
    t[ty + j][tx] = W[(size_t)(blockIdx.y * 32 + ty + j) * DM + blockIdx.x * 32 + tx];
  __syncthreads();
#pragma unroll
  for (int j = 0; j < 32; j += 8)
    Wt[(size_t)(blockIdx.x * 32 + ty + j) * DM + blockIdx.y * 32 + tx] = f2bf(t[tx][ty + j]);
}

// ---------------- GEMM core: BK=64, f32-A fused convert, A-reg PREFETCH ----
// 32 MFMA per barrier-pair, 16 K-steps. LDS rows are 128 B -> XOR swizzle:
// B staged via global_load_lds with pre-swizzled source chunk
// ((lane&7)^(lane>>3)); A written by ds_write_b128 at chunk c^(row&7)
// (8 consecutive lanes cover all 8 chunks -> conflict-free); fragment reads
// XOR (lr&7). Per K-step: (1) B async, (2) cvt+swizzled-write A regs,
// (3) prefetch next A regs, (4) barrier.
// EPI 0: bf16 row-major; EPI 1: bf16 scatter Vt[(b*DM+col)*S_+s].
template <int EPI>
__device__ __forceinline__ void gemm_body(const float* __restrict__ A,
                                          const u16* __restrict__ Bt,
                                          const float* __restrict__ bias,
                                          void* __restrict__ Cout,
                                          int M, int N, int K, float oscale,
                                          int bx, int by) {
  __shared__ u16 lA[128 * 64];
  __shared__ u16 lB[128 * 64];
  const int tid = threadIdx.x, wid = tid >> 6, lane = tid & 63;
  const int lr = lane & 15, lh = lane >> 4;
  const int m0 = by * 128, n0 = bx * 128;
  const int wr = wid >> 1, wc = wid & 1;

  f32x4 acc[4][4];
#pragma unroll
  for (int m = 0; m < 4; m++)
#pragma unroll
    for (int n = 0; n < 4; n++) acc[m][n] = (f32x4){0.f, 0.f, 0.f, 0.f};

  // B staging: wave w, instr p covers rows w*32+p*8 .. +8; lane -> row
  // (lane>>3), chunk (lane&7)^(lane>>3) pre-swizzled ((row&7)==(lane>>3)).
  const int sbrow = wid * 32 + (lane >> 3);
  const u16* Bs = Bt + (size_t)(n0 + sbrow) * K + ((lane & 7) ^ (lane >> 3)) * 8;
  u16* lBw = lB + (wid * 32) * 64;

  // A staging: row = w*32 + (lane>>1); half (lane&1) covers chunks 4h..4h+3.
  const int sar = wid * 32 + (lane >> 1);
  const int cb4 = (lane & 1) * 4;
  const int rx = sar & 7;
  const float* As = A + (size_t)(m0 + sar) * K + cb4 * 8;
  u16* lArow = lA + (size_t)sar * 64;

  f32x4 ar[8];
#pragma unroll
  for (int j = 0; j < 8; j++) ar[j] = *(const f32x4*)(As + j * 4);

  const int sxr = (lr & 7) * 8;   // read-side XOR (u16 units)

  for (int k0 = 0; k0 < K; k0 += 64) {
    // (1) B async direct-to-LDS
#pragma unroll
    for (int p = 0; p < 4; p++)
      gload_lds16(Bs + (size_t)(p * 8) * K + k0, lBw + p * 8 * 64);
    // (2) convert + swizzled-write current A regs
#pragma unroll
    for (int j = 0; j < 4; j++) {
      u32x4 wv = {cvtpk(ar[2 * j].x, ar[2 * j].y),
                  cvtpk(ar[2 * j].z, ar[2 * j].w),
                  cvtpk(ar[2 * j + 1].x, ar[2 * j + 1].y),
                  cvtpk(ar[2 * j + 1].z, ar[2 * j + 1].w)};
      *(u32x4*)(lArow + ((cb4 + j) ^ rx) * 8) = wv;
    }
    // (3) prefetch next K-step's A
    if (k0 + 64 < K) {
#pragma unroll
      for (int j = 0; j < 8; j++)
        ar[j] = *(const f32x4*)(As + k0 + 64 + j * 4);
    }
    __syncthreads();
#pragma unroll
    for (int s = 0; s < 2; s++) {
      short8 af[4], bf[4];
#pragma unroll
      for (int m = 0; m < 4; m++)
        af[m] = *(const short8*)(lA + (wr * 64 + m * 16 + lr) * 64 + ((s * 32 + lh * 8) ^ sxr));
#pragma unroll
      for (int n = 0; n < 4; n++)
        bf[n] = *(const short8*)(lB + (wc * 64 + n * 16 + lr) * 64 + ((s * 32 + lh * 8) ^ sxr));
#pragma unroll
      for (int m = 0; m < 4; m++)
#pragma unroll
        for (int n = 0; n < 4; n++) acc[m][n] = mfma16(af[m], bf[n], acc[m][n]);
    }
    __syncthreads();
  }

#pragma unroll
  for (int m = 0; m < 4; m++) {
    int grow0 = m0 + wr * 64 + m * 16 + lh * 4;
#pragma unroll
    for (int n = 0; n < 4; n++) {
      int gcol = n0 + wc * 64 + n * 16 + lr;
      float bi = bias[gcol];
      float v0 = (acc[m][n][0] + bi) * oscale;
      float v1 = (acc[m][n][1] + bi) * oscale;
      float v2 = (acc[m][n][2] + bi) * oscale;
      float v3 = (acc[m][n][3] + bi) * oscale;
      u32 p01 = cvtpk(v0, v1), p23 = cvtpk(v2, v3);
      u16* C = (u16*)Cout;
#pragma unroll
      for (int r = 0; r < 4; r++) {
        u32 pk = r < 2 ? p01 : p23;
        u16 bv = (r & 1) ? (u16)(pk >> 16) : (u16)(pk & 0xffff);
        int grow = grow0 + r;
        if constexpr (EPI == 0) {
          C[(size_t)grow * N + gcol] = bv;
        } else {
          int bb = grow >> 11, sl = grow & 2047;
          C[((size_t)(bb * DM) + gcol) * S_ + sl] = bv;
        }
      }
    }
  }
}

__global__ __launch_bounds__(256) void gemm_qkv(
    const float* __restrict__ q, const float* __restrict__ k, const float* __restrict__ v,
    const u16* __restrict__ WqT, const u16* __restrict__ WkT, const u16* __restrict__ WvT,
    const float* __restrict__ bq, const float* __restrict__ bk, const float* __restrict__ bv,
    u16* __restrict__ Qp, u16* __restrict__ Kp, u16* __restrict__ Vt, float qsc) {
  int lin = blockIdx.x;                       // 1536 = 8*64*3
  int swz = (lin & 7) * 192 + (lin >> 3);     // bijective (1536 % 8 == 0)
  const int bx = swz & 7, by = (swz >> 3) & 63, z = swz >> 9;
  if (z == 0)
    gemm_body<0>(q, WqT, bq, Qp, B_ * L_, DM, DM, qsc, bx, by);
  else if (z == 1)
    gemm_body<0>(k, WkT, bk, Kp, B_ * L_, DM, DM, 1.0f, bx, by);
  else
    gemm_body<1>(v, WvT, bv, Vt, B_ * L_, DM, DM, 1.0f, bx, by);
}

// ---------------- output projection: 128x128 tile, BK=128 (R18) ------------
__global__ __launch_bounds__(256) void gemm_out(const u16* __restrict__ A,
                                                const u16* __restrict__ Bt,
                                                const float* __restrict__ bias,
                                                float* __restrict__ C) {
  const int N = DM, K = DM;
  int lin = blockIdx.x;                       // 512 = 8*64
  int swz = (lin & 7) * 64 + (lin >> 3);      // bijective
  const int bx = swz & 7, by = swz >> 3;

  __shared__ u16 lA[128 * 128];
  __shared__ u16 lB[128 * 128];
  const int tid = threadIdx.x, wid = tid >> 6, lane = tid & 63;
  const int lr = lane & 15, lh = lane >> 4;
  const int m0 = by * 128, n0 = bx * 128;
  const int wr = wid >> 1, wc = wid & 1;

  f32x4 acc[4][4];
#pragma unroll
  for (int m = 0; m < 4; m++)
#pragma unroll
    for (int n = 0; n < 4; n++) acc[m][n] = (f32x4){0.f, 0.f, 0.f, 0.f};

  const int srw = wid * 4 + (lane >> 4);              // row within 16-group
  const int scx = ((lane & 15) ^ (srw & 15)) * 8;     // source chunk (u16)
  const u16* As = A + (size_t)(m0 + srw) * K + scx;
  const u16* Bs = Bt + (size_t)(n0 + srw) * K + scx;
  u16* lAw = lA + (wid * 4) * 128;
  u16* lBw = lB + (wid * 4) * 128;

  for (int k0 = 0; k0 < K; k0 += 128) {
#pragma unroll
    for (int p = 0; p < 8; p++) {
      gload_lds16(As + (size_t)(p * 16) * K + k0, lAw + p * 16 * 128);
      gload_lds16(Bs + (size_t)(p * 16) * K + k0, lBw + p * 16 * 128);
    }
    __syncthreads();
#pragma unroll
    for (int s = 0; s < 4; s++) {
      short8 af[4], bf[4];
#pragma unroll
      for (int m = 0; m < 4; m++)
        af[m] = *(const short8*)(lA + (wr * 64 + m * 16 + lr) * 128 + ((s * 4 + lh) ^ lr) * 8);
#pragma unroll
      for (int n = 0; n < 4; n++)
        bf[n] = *(const short8*)(lB + (wc * 64 + n * 16 + lr) * 128 + ((s * 4 + lh) ^ lr) * 8);
#pragma unroll
      for (int m = 0; m < 4; m++)
#pragma unroll
        for (int n = 0; n < 4; n++) acc[m][n] = mfma16(af[m], bf[n], acc[m][n]);
    }
    __syncthreads();
  }

#pragma unroll
  for (int m = 0; m < 4; m++) {
    int grow0 = m0 + wr * 64 + m * 16 + lh * 4;
#pragma unroll
    for (int n = 0; n < 4; n++) {
      int gcol = n0 + wc * 64 + n * 16 + lr;
      float bi = bias[gcol];
#pragma unroll
      for (int r = 0; r < 4; r++)
        C[(size_t)(grow0 + r) * N + gcol] = acc[m][n][r] + bi;
    }
  }
}

// ---------------- flash attention, 32x32x16 MFMA, 8 waves x 32 q -----------
// (R6 structure, verbatim: the 103.8 us configuration.)
__global__ __launch_bounds__(512) void attn(const u16* __restrict__ Q,
                                            const u16* __restrict__ Kp,
                                            const u16* __restrict__ Vt,
                                            u16* __restrict__ O) {
  __shared__ u16 lK[2][64 * 64];
  __shared__ u16 lV[2][64 * 64];
  const int tid = threadIdx.x, wid = tid >> 6, lane = tid & 63;
  const int l31 = lane & 31, hi = lane >> 5;

  int lin = blockIdx.x;
  int swz = (lin & 7) * 64 + (lin >> 3);
  const int bh = swz >> 3, q0 = (swz & 7) * 256;
  const int b = bh >> 4, h = bh & 15;
  const int qrow = q0 + wid * 32 + l31;

  const u16* Qb = Q + ((size_t)(b * L_ + qrow)) * DM + h * E_ + hi * 8;
  short8 qf[4];
#pragma unroll
  for (int s = 0; s < 4; s++) qf[s] = *(const short8*)(Qb + s * 16);

  f32x16 o[2];
#pragma unroll
  for (int et = 0; et < 2; et++)
#pragma unroll
    for (int r = 0; r < 16; r++) o[et][r] = 0.f;
  float m_r = -3.0e38f, l_r = 0.f;

  const u16* Kb = Kp + ((size_t)(b * S_)) * DM + h * E_;
  const u16* Vb = Vt + ((size_t)(b * DM + h * E_)) * S_;

  const int srow = wid * 8 + (lane >> 3);
  const u16* srcK = Kb + (size_t)srow * DM + ((lane & 7) ^ (srow & 7)) * 8;
  const u16* srcV = Vb + (size_t)srow * S_ + ((lane & 7) ^ (srow & 7)) * 8;

  const int sxk = (l31 & 7) * 8;   // read-side XOR (u16 units)
  const int hi4 = hi * 4, hi8 = hi * 8;

  auto stage = [&](int buf, int kb) {
    gload_lds16(srcK + (size_t)kb * DM, lK[buf] + wid * 512);
    gload_lds16(srcV + kb, lV[buf] + wid * 512);
  };

  stage(0, 0);
  const int NT = S_ / 64;  // 32
  for (int it = 0; it < NT; ++it) {
    const int buf = it & 1;
    __syncthreads();
    if (it + 1 < NT) stage(buf ^ 1, (it + 1) * 64);

    // QK^T: 2 k-subtiles of 32, K-dim 64 = 4 steps of 16
    f32x16 sc[2];
    const u16* kbase = lK[buf] + l31 * 64;
    __builtin_amdgcn_s_setprio(1);
#pragma unroll
    for (int kt = 0; kt < 2; kt++) {
      f32x16 a;
#pragma unroll
      for (int r = 0; r < 16; r++) a[r] = 0.f;
#pragma unroll
      for (int s = 0; s < 4; s++) {
        short8 kf = *(const short8*)(kbase + kt * 2048 + ((s * 16 + hi8) ^ sxk));
        a = mfma32(kf, qf[s], a);
      }
      sc[kt] = a;
    }
    __builtin_amdgcn_s_setprio(0);

    // tile max: vector tree + cross-half shfl
    f32x16 mA;
#pragma unroll
    for (int r = 0; r < 16; r++) mA[r] = fmaxf(sc[0][r], sc[1][r]);
#pragma unroll
    for (int r = 0; r < 8; r++) mA[r] = fmaxf(mA[r], mA[r + 8]);
#pragma unroll
    for (int r = 0; r < 4; r++) mA[r] = fmaxf(mA[r], mA[r + 4]);
    float tm = fmaxf(fmaxf(mA[0], mA[1]), fmaxf(mA[2], mA[3]));
    tm = fmaxf(tm, __shfl_xor(tm, 32));

    // defer-max rescale (log2 domain, THR=8)
    if (__any(tm > m_r + 8.f)) {
      float mn = fmaxf(m_r, tm);
      float al = exp2a(m_r - mn);
      m_r = mn;
      l_r *= al;
#pragma unroll
      for (int et = 0; et < 2; et++)
#pragma unroll
        for (int r = 0; r < 16; r++) o[et][r] *= al;
    }

    // p = exp2(s - m); pack pairs -> PV B-frag words (in-register, no LDS)
    u32 wp[2][8];
    float rs = 0.f;
#pragma unroll
    for (int kt = 0; kt < 2; kt++)
#pragma unroll
      for (int i = 0; i < 8; i++) {
        float p0 = exp2a(sc[kt][2 * i] - m_r);
        float p1 = exp2a(sc[kt][2 * i + 1] - m_r);
        rs += p0 + p1;
        wp[kt][i] = cvtpk(p0, p1);
      }
    rs += __shfl_xor(rs, 32);
    l_r += rs;

    // PV: out[e][q] += V^T * P, contraction relabeled to match reg layout
    __builtin_amdgcn_s_setprio(1);
#pragma unroll
    for (int et = 0; et < 2; et++) {
      const u16* vp = lV[buf] + (et * 32 + l31) * 64;
#pragma unroll
      for (int kt = 0; kt < 2; kt++)
#pragma unroll
        for (int su = 0; su < 2; su++) {
          int koff = kt * 32 + su * 16 + hi4;
          u32x2 lo = *(const u32x2*)(vp + (koff ^ sxk));
          u32x2 hp = *(const u32x2*)(vp + ((koff + 8) ^ sxk));
          u32x4 vv = {lo.x, lo.y, hp.x, hp.y};
          u32x4 pv = {wp[kt][su * 4 + 0], wp[kt][su * 4 + 1],
                      wp[kt][su * 4 + 2], wp[kt][su * 4 + 3]};
          o[et] = mfma32(*(const short8*)&vv, *(const short8*)&pv, o[et]);
        }
    }
    __builtin_amdgcn_s_setprio(0);
  }

  // epilogue: lane-local normalize; o reg r -> e = (r&3)+8*(r>>2)+4*hi+32*et
  float inv = 1.f / l_r;
  u16* Ob = O + ((size_t)(b * L_ + qrow)) * DM + h * E_;
#pragma unroll
  for (int et = 0; et < 2; et++)
#pragma unroll
    for (int t = 0; t < 4; t++) {
      u32x2 pk;
      pk.x = cvtpk(o[et][4 * t] * inv, o[et][4 * t + 1] * inv);
      pk.y = cvtpk(o[et][4 * t + 2] * inv, o[et][4 * t + 3] * inv);
      *(u32x2*)(Ob + et * 32 + t * 8 + hi4) = pk;
    }
}

extern "C" void kernel_launch(void* const* d_in, const int* in_sizes, int n_in,
                              void* d_out, int out_size, void* d_ws, size_t ws_size,
                              hipStream_t stream) {
  (void)in_sizes; (void)n_in; (void)out_size; (void)ws_size;
  const float* q  = (const float*)d_in[0];
  const float* k  = (const float*)d_in[1];
  const float* v  = (const float*)d_in[2];
  const float* Wq = (const float*)d_in[3];
  const float* bq = (const float*)d_in[4];
  const float* Wk = (const float*)d_in[5];
  const float* bk = (const float*)d_in[6];
  const float* Wv = (const float*)d_in[7];
  const float* bv = (const float*)d_in[8];
  const float* Wo = (const float*)d_in[9];
  const float* bo = (const float*)d_in[10];

  char* w = (char*)d_ws;
  const size_t ACT = (size_t)B_ * L_ * DM * 2;  // 16 MiB
  const size_t WT  = (size_t)DM * DM * 2;       // 2 MiB
  u16* WqT = (u16*)w; w += WT;
  u16* WkT = (u16*)w; w += WT;
  u16* WvT = (u16*)w; w += WT;
  u16* WoT = (u16*)w; w += WT;
  u16* Qp  = (u16*)w; w += ACT;
  u16* Kp  = (u16*)w; w += ACT;
  u16* Vt  = (u16*)w; w += ACT;
  u16* At  = (u16*)w; w += ACT;

  transp_all<<<dim3(32, 32, 4), 256, 0, stream>>>(Wq, Wk, Wv, Wo, WqT, WkT, WvT, WoT);

  const float QSC = 0.125f * 1.44269504089f;  // 1/sqrt(64) * log2(e)
  gemm_qkv<<<dim3(1536), 256, 0, stream>>>(
      q, k, v, WqT, WkT, WvT, bq, bk, bv, Qp, Kp, Vt, QSC);

  attn<<<dim3(512), 512, 0, stream>>>(Qp, Kp, Vt, At);

  gemm_out<<<dim3(512), 256, 0, stream>>>(At, WoT, bo, (float*)d_out);
}

// Round 21
// 205.610 us; speedup vs baseline: 1.2416x; 1.2416x over previous
//
#include <hip/hip_runtime.h>
#include <hip/hip_bf16.h>

typedef unsigned short u16;
typedef unsigned int u32;
using short8 = __attribute__((ext_vector_type(8))) short;
using f32x4  = __attribute__((ext_vector_type(4))) float;
using f32x16 = __attribute__((ext_vector_type(16))) float;
using u32x2  = __attribute__((ext_vector_type(2))) unsigned int;
using u32x4  = __attribute__((ext_vector_type(4))) unsigned int;

#define B_  4
#define L_  2048
#define S_  2048
#define DM  1024
#define H_  16
#define E_  64

__device__ __forceinline__ u16 f2bf(float f) {
  union { float f; unsigned u; } v; v.f = f;
  unsigned u = v.u;
  unsigned r = (u + 0x7fffu + ((u >> 16) & 1u)) >> 16;  // RNE
  return (u16)r;
}

__device__ __forceinline__ float exp2a(float x) {
  float r; asm("v_exp_f32 %0, %1" : "=v"(r) : "v"(x)); return r;
}

__device__ __forceinline__ u32 cvtpk(float lo, float hi) {
  u32 r; asm("v_cvt_pk_bf16_f32 %0, %1, %2" : "=v"(r) : "v"(lo), "v"(hi));
  return r;
}

__device__ __forceinline__ f32x4 mfma16(short8 a, short8 b, f32x4 c) {
  return __builtin_amdgcn_mfma_f32_16x16x32_bf16(a, b, c, 0, 0, 0);
}

__device__ __forceinline__ f32x16 mfma32(short8 a, short8 b, f32x16 c) {
  return __builtin_amdgcn_mfma_f32_32x32x16_bf16(a, b, c, 0, 0, 0);
}

__device__ __forceinline__ void gload_lds16(const u16* g, u16* l) {
  __builtin_amdgcn_global_load_lds(
      (const __attribute__((address_space(1))) unsigned int*)(const void*)g,
      (__attribute__((address_space(3))) unsigned int*)(void*)l, 16, 0, 0);
}

// ---------------- fused weight transpose+convert (one launch, z=4) ---------
__global__ __launch_bounds__(256) void transp_all(const float* __restrict__ w0,
                                                  const float* __restrict__ w1,
                                                  const float* __restrict__ w2,
                                                  const float* __restrict__ w3,
                                                  u16* __restrict__ t0,
                                                  u16* __restrict__ t1,
                                                  u16* __restrict__ t2,
                                                  u16* __restrict__ t3) {
  const float* W = blockIdx.z == 0 ? w0 : blockIdx.z == 1 ? w1 :
                   blockIdx.z == 2 ? w2 : w3;
  u16* Wt = blockIdx.z == 0 ? t0 : blockIdx.z == 1 ? t1 :
            blockIdx.z == 2 ? t2 : t3;
  __shared__ float t[32][33];
  int tx = threadIdx.x & 31, ty = (threadIdx.x >> 5) & 7;
#pragma unroll
  for (int j = 0; j < 32; j += 8)
    t[ty + j][tx] = W[(size_t)(blockIdx.y * 32 + ty + j) * DM + blockIdx.x * 32 + tx];
  __syncthreads();
#pragma unroll
  for (int j = 0; j < 32; j += 8)
    Wt[(size_t)(blockIdx.x * 32 + ty + j) * DM + blockIdx.y * 32 + tx] = f2bf(t[tx][ty + j]);
}

// ---------------- GEMM core (f32-A fused convert, A-reg PREFETCH, BK=32) ---
// Per K-step: (1) B global_load_lds (async), (2) cvt+ds_write current A regs,
// (3) issue next A reg-loads, (4) barrier. 32 KB LDS -> 5 blocks/CU
// residency (grid 1536 = 6/CU desired; BK=64's 64 KB halved residency and
// regressed -- R19 lesson). EPI 0: bf16 row-major; EPI 1: bf16 scatter Vt.
template <int EPI>
__device__ __forceinline__ void gemm_body(const float* __restrict__ A,
                                          const u16* __restrict__ Bt,
                                          const float* __restrict__ bias,
                                          void* __restrict__ Cout,
                                          int M, int N, int K, float oscale,
                                          int bx, int by) {
  __shared__ u16 lA[128 * 32];
  __shared__ u16 lB[128 * 32];
  const int tid = threadIdx.x, wid = tid >> 6, lane = tid & 63;
  const int lr = lane & 15, lh = lane >> 4;
  const int m0 = by * 128, n0 = bx * 128;
  const int wr = wid >> 1, wc = wid & 1;

  f32x4 acc[4][4];
#pragma unroll
  for (int m = 0; m < 4; m++)
#pragma unroll
    for (int n = 0; n < 4; n++) acc[m][n] = (f32x4){0.f, 0.f, 0.f, 0.f};

  const int srow = wid * 16 + (lane >> 2);
  const int scol = (lane & 3) * 8;

  const float* a0p = A + (size_t)(m0 + srow) * K + scol;
  const float* a1p = A + (size_t)(m0 + 64 + srow) * K + scol;

  f32x4 r00 = *(const f32x4*)a0p;
  f32x4 r01 = *(const f32x4*)(a0p + 4);
  f32x4 r10 = *(const f32x4*)a1p;
  f32x4 r11 = *(const f32x4*)(a1p + 4);

  for (int k0 = 0; k0 < K; k0 += 32) {
    gload_lds16(Bt + (size_t)(n0 + srow) * K + k0 + scol, lB + (wid * 16) * 32);
    gload_lds16(Bt + (size_t)(n0 + 64 + srow) * K + k0 + scol, lB + (64 + wid * 16) * 32);
    u32x4 w0 = {cvtpk(r00.x, r00.y), cvtpk(r00.z, r00.w),
                cvtpk(r01.x, r01.y), cvtpk(r01.z, r01.w)};
    u32x4 w1 = {cvtpk(r10.x, r10.y), cvtpk(r10.z, r10.w),
                cvtpk(r11.x, r11.y), cvtpk(r11.z, r11.w)};
    *(u32x4*)(lA + (size_t)srow * 32 + scol) = w0;
    *(u32x4*)(lA + (size_t)(64 + srow) * 32 + scol) = w1;
    if (k0 + 32 < K) {
      r00 = *(const f32x4*)(a0p + k0 + 32);
      r01 = *(const f32x4*)(a0p + k0 + 36);
      r10 = *(const f32x4*)(a1p + k0 + 32);
      r11 = *(const f32x4*)(a1p + k0 + 36);
    }
    __syncthreads();
    short8 af[4], bf[4];
#pragma unroll
    for (int m = 0; m < 4; m++)
      af[m] = *(const short8*)(lA + (wr * 64 + m * 16 + lr) * 32 + lh * 8);
#pragma unroll
    for (int n = 0; n < 4; n++)
      bf[n] = *(const short8*)(lB + (wc * 64 + n * 16 + lr) * 32 + lh * 8);
#pragma unroll
    for (int m = 0; m < 4; m++)
#pragma unroll
      for (int n = 0; n < 4; n++) acc[m][n] = mfma16(af[m], bf[n], acc[m][n]);
    __syncthreads();
  }

#pragma unroll
  for (int m = 0; m < 4; m++) {
    int grow0 = m0 + wr * 64 + m * 16 + lh * 4;
#pragma unroll
    for (int n = 0; n < 4; n++) {
      int gcol = n0 + wc * 64 + n * 16 + lr;
      float bi = bias[gcol];
      float v0 = (acc[m][n][0] + bi) * oscale;
      float v1 = (acc[m][n][1] + bi) * oscale;
      float v2 = (acc[m][n][2] + bi) * oscale;
      float v3 = (acc[m][n][3] + bi) * oscale;
      u32 p01 = cvtpk(v0, v1), p23 = cvtpk(v2, v3);
      u16* C = (u16*)Cout;
#pragma unroll
      for (int r = 0; r < 4; r++) {
        u32 pk = r < 2 ? p01 : p23;
        u16 bv = (r & 1) ? (u16)(pk >> 16) : (u16)(pk & 0xffff);
        int grow = grow0 + r;
        if constexpr (EPI == 0) {
          C[(size_t)grow * N + gcol] = bv;
        } else {
          int bb = grow >> 11, sl = grow & 2047;
          C[((size_t)(bb * DM) + gcol) * S_ + sl] = bv;
        }
      }
    }
  }
}

__global__ __launch_bounds__(256) void gemm_qkv(
    const float* __restrict__ q, const float* __restrict__ k, const float* __restrict__ v,
    const u16* __restrict__ WqT, const u16* __restrict__ WkT, const u16* __restrict__ WvT,
    const float* __restrict__ bq, const float* __restrict__ bk, const float* __restrict__ bv,
    u16* __restrict__ Qp, u16* __restrict__ Kp, u16* __restrict__ Vt, float qsc) {
  int lin = blockIdx.x;                       // 1536 = 8*64*3
  int swz = (lin & 7) * 192 + (lin >> 3);     // bijective (1536 % 8 == 0)
  const int bx = swz & 7, by = (swz >> 3) & 63, z = swz >> 9;
  if (z == 0)
    gemm_body<0>(q, WqT, bq, Qp, B_ * L_, DM, DM, qsc, bx, by);
  else if (z == 1)
    gemm_body<0>(k, WkT, bk, Kp, B_ * L_, DM, DM, 1.0f, bx, by);
  else
    gemm_body<1>(v, WvT, bv, Vt, B_ * L_, DM, DM, 1.0f, bx, by);
}

// ---------------- output projection: 128x128 tile, BK=128 ------------------
// 64 MFMA per barrier-pair, 8 K-steps. Grid 512 = 2 blocks/CU (grid-capped),
// so the 64 KB LDS costs nothing. Rows are 256 B -> full 16-way XOR swizzle.
__global__ __launch_bounds__(256) void gemm_out(const u16* __restrict__ A,
                                                const u16* __restrict__ Bt,
                                                const float* __restrict__ bias,
                                                float* __restrict__ C) {
  const int N = DM, K = DM;
  int lin = blockIdx.x;                       // 512 = 8*64
  int swz = (lin & 7) * 64 + (lin >> 3);      // bijective
  const int bx = swz & 7, by = swz >> 3;

  __shared__ u16 lA[128 * 128];
  __shared__ u16 lB[128 * 128];
  const int tid = threadIdx.x, wid = tid >> 6, lane = tid & 63;
  const int lr = lane & 15, lh = lane >> 4;
  const int m0 = by * 128, n0 = bx * 128;
  const int wr = wid >> 1, wc = wid & 1;

  f32x4 acc[4][4];
#pragma unroll
  for (int m = 0; m < 4; m++)
#pragma unroll
    for (int n = 0; n < 4; n++) acc[m][n] = (f32x4){0.f, 0.f, 0.f, 0.f};

  const int srw = wid * 4 + (lane >> 4);              // row within 16-group
  const int scx = ((lane & 15) ^ (srw & 15)) * 8;     // source chunk (u16)
  const u16* As = A + (size_t)(m0 + srw) * K + scx;
  const u16* Bs = Bt + (size_t)(n0 + srw) * K + scx;
  u16* lAw = lA + (wid * 4) * 128;
  u16* lBw = lB + (wid * 4) * 128;

  for (int k0 = 0; k0 < K; k0 += 128) {
#pragma unroll
    for (int p = 0; p < 8; p++) {
      gload_lds16(As + (size_t)(p * 16) * K + k0, lAw + p * 16 * 128);
      gload_lds16(Bs + (size_t)(p * 16) * K + k0, lBw + p * 16 * 128);
    }
    __syncthreads();
#pragma unroll
    for (int s = 0; s < 4; s++) {
      short8 af[4], bf[4];
#pragma unroll
      for (int m = 0; m < 4; m++)
        af[m] = *(const short8*)(lA + (wr * 64 + m * 16 + lr) * 128 + ((s * 4 + lh) ^ lr) * 8);
#pragma unroll
      for (int n = 0; n < 4; n++)
        bf[n] = *(const short8*)(lB + (wc * 64 + n * 16 + lr) * 128 + ((s * 4 + lh) ^ lr) * 8);
#pragma unroll
      for (int m = 0; m < 4; m++)
#pragma unroll
        for (int n = 0; n < 4; n++) acc[m][n] = mfma16(af[m], bf[n], acc[m][n]);
    }
    __syncthreads();
  }

#pragma unroll
  for (int m = 0; m < 4; m++) {
    int grow0 = m0 + wr * 64 + m * 16 + lh * 4;
#pragma unroll
    for (int n = 0; n < 4; n++) {
      int gcol = n0 + wc * 64 + n * 16 + lr;
      float bi = bias[gcol];
#pragma unroll
      for (int r = 0; r < 4; r++)
        C[(size_t)(grow0 + r) * N + gcol] = acc[m][n][r] + bi;
    }
  }
}

// ---------------- flash attention, 32x32x16 MFMA, 8 waves x 32 q -----------
// (R6 structure, verbatim: the 103.8 us configuration.)
__global__ __launch_bounds__(512) void attn(const u16* __restrict__ Q,
                                            const u16* __restrict__ Kp,
                                            const u16* __restrict__ Vt,
                                            u16* __restrict__ O) {
  __shared__ u16 lK[2][64 * 64];
  __shared__ u16 lV[2][64 * 64];
  const int tid = threadIdx.x, wid = tid >> 6, lane = tid & 63;
  const int l31 = lane & 31, hi = lane >> 5;

  int lin = blockIdx.x;
  int swz = (lin & 7) * 64 + (lin >> 3);
  const int bh = swz >> 3, q0 = (swz & 7) * 256;
  const int b = bh >> 4, h = bh & 15;
  const int qrow = q0 + wid * 32 + l31;

  const u16* Qb = Q + ((size_t)(b * L_ + qrow)) * DM + h * E_ + hi * 8;
  short8 qf[4];
#pragma unroll
  for (int s = 0; s < 4; s++) qf[s] = *(const short8*)(Qb + s * 16);

  f32x16 o[2];
#pragma unroll
  for (int et = 0; et < 2; et++)
#pragma unroll
    for (int r = 0; r < 16; r++) o[et][r] = 0.f;
  float m_r = -3.0e38f, l_r = 0.f;

  const u16* Kb = Kp + ((size_t)(b * S_)) * DM + h * E_;
  const u16* Vb = Vt + ((size_t)(b * DM + h * E_)) * S_;

  const int srow = wid * 8 + (lane >> 3);
  const u16* srcK = Kb + (size_t)srow * DM + ((lane & 7) ^ (srow & 7)) * 8;
  const u16* srcV = Vb + (size_t)srow * S_ + ((lane & 7) ^ (srow & 7)) * 8;

  const int sxk = (l31 & 7) * 8;   // read-side XOR (u16 units)
  const int hi4 = hi * 4, hi8 = hi * 8;

  auto stage = [&](int buf, int kb) {
    gload_lds16(srcK + (size_t)kb * DM, lK[buf] + wid * 512);
    gload_lds16(srcV + kb, lV[buf] + wid * 512);
  };

  stage(0, 0);
  const int NT = S_ / 64;  // 32
  for (int it = 0; it < NT; ++it) {
    const int buf = it & 1;
    __syncthreads();
    if (it + 1 < NT) stage(buf ^ 1, (it + 1) * 64);

    // QK^T: 2 k-subtiles of 32, K-dim 64 = 4 steps of 16
    f32x16 sc[2];
    const u16* kbase = lK[buf] + l31 * 64;
    __builtin_amdgcn_s_setprio(1);
#pragma unroll
    for (int kt = 0; kt < 2; kt++) {
      f32x16 a;
#pragma unroll
      for (int r = 0; r < 16; r++) a[r] = 0.f;
#pragma unroll
      for (int s = 0; s < 4; s++) {
        short8 kf = *(const short8*)(kbase + kt * 2048 + ((s * 16 + hi8) ^ sxk));
        a = mfma32(kf, qf[s], a);
      }
      sc[kt] = a;
    }
    __builtin_amdgcn_s_setprio(0);

    // tile max: vector tree + cross-half shfl
    f32x16 mA;
#pragma unroll
    for (int r = 0; r < 16; r++) mA[r] = fmaxf(sc[0][r], sc[1][r]);
#pragma unroll
    for (int r = 0; r < 8; r++) mA[r] = fmaxf(mA[r], mA[r + 8]);
#pragma unroll
    for (int r = 0; r < 4; r++) mA[r] = fmaxf(mA[r], mA[r + 4]);
    float tm = fmaxf(fmaxf(mA[0], mA[1]), fmaxf(mA[2], mA[3]));
    tm = fmaxf(tm, __shfl_xor(tm, 32));

    // defer-max rescale (log2 domain, THR=8)
    if (__any(tm > m_r + 8.f)) {
      float mn = fmaxf(m_r, tm);
      float al = exp2a(m_r - mn);
      m_r = mn;
      l_r *= al;
#pragma unroll
      for (int et = 0; et < 2; et++)
#pragma unroll
        for (int r = 0; r < 16; r++) o[et][r] *= al;
    }

    // p = exp2(s - m); pack pairs -> PV B-frag words (in-register, no LDS)
    u32 wp[2][8];
    float rs = 0.f;
#pragma unroll
    for (int kt = 0; kt < 2; kt++)
#pragma unroll
      for (int i = 0; i < 8; i++) {
        float p0 = exp2a(sc[kt][2 * i] - m_r);
        float p1 = exp2a(sc[kt][2 * i + 1] - m_r);
        rs += p0 + p1;
        wp[kt][i] = cvtpk(p0, p1);
      }
    rs += __shfl_xor(rs, 32);
    l_r += rs;

    // PV: out[e][q] += V^T * P, contraction relabeled to match reg layout
    __builtin_amdgcn_s_setprio(1);
#pragma unroll
    for (int et = 0; et < 2; et++) {
      const u16* vp = lV[buf] + (et * 32 + l31) * 64;
#pragma unroll
      for (int kt = 0; kt < 2; kt++)
#pragma unroll
        for (int su = 0; su < 2; su++) {
          int koff = kt * 32 + su * 16 + hi4;
          u32x2 lo = *(const u32x2*)(vp + (koff ^ sxk));
          u32x2 hp = *(const u32x2*)(vp + ((koff + 8) ^ sxk));
          u32x4 vv = {lo.x, lo.y, hp.x, hp.y};
          u32x4 pv = {wp[kt][su * 4 + 0], wp[kt][su * 4 + 1],
                      wp[kt][su * 4 + 2], wp[kt][su * 4 + 3]};
          o[et] = mfma32(*(const short8*)&vv, *(const short8*)&pv, o[et]);
        }
    }
    __builtin_amdgcn_s_setprio(0);
  }

  // epilogue: lane-local normalize; o reg r -> e = (r&3)+8*(r>>2)+4*hi+32*et
  float inv = 1.f / l_r;
  u16* Ob = O + ((size_t)(b * L_ + qrow)) * DM + h * E_;
#pragma unroll
  for (int et = 0; et < 2; et++)
#pragma unroll
    for (int t = 0; t < 4; t++) {
      u32x2 pk;
      pk.x = cvtpk(o[et][4 * t] * inv, o[et][4 * t + 1] * inv);
      pk.y = cvtpk(o[et][4 * t + 2] * inv, o[et][4 * t + 3] * inv);
      *(u32x2*)(Ob + et * 32 + t * 8 + hi4) = pk;
    }
}

extern "C" void kernel_launch(void* const* d_in, const int* in_sizes, int n_in,
                              void* d_out, int out_size, void* d_ws, size_t ws_size,
                              hipStream_t stream) {
  (void)in_sizes; (void)n_in; (void)out_size; (void)ws_size;
  const float* q  = (const float*)d_in[0];
  const float* k  = (const float*)d_in[1];
  const float* v  = (const float*)d_in[2];
  const float* Wq = (const float*)d_in[3];
  const float* bq = (const float*)d_in[4];
  const float* Wk = (const float*)d_in[5];
  const float* bk = (const float*)d_in[6];
  const float* Wv = (const float*)d_in[7];
  const float* bv = (const float*)d_in[8];
  const float* Wo = (const float*)d_in[9];
  const float* bo = (const float*)d_in[10];

  char* w = (char*)d_ws;
  const size_t ACT = (size_t)B_ * L_ * DM * 2;  // 16 MiB
  const size_t WT  = (size_t)DM * DM * 2;       // 2 MiB
  u16* WqT = (u16*)w; w += WT;
  u16* WkT = (u16*)w; w += WT;
  u16* WvT = (u16*)w; w += WT;
  u16* WoT = (u16*)w; w += WT;
  u16* Qp  = (u16*)w; w += ACT;
  u16* Kp  = (u16*)w; w += ACT;
  u16* Vt  = (u16*)w; w += ACT;
  u16* At  = (u16*)w; w += ACT;

  transp_all<<<dim3(32, 32, 4), 256, 0, stream>>>(Wq, Wk, Wv, Wo, WqT, WkT, WvT, WoT);

  const float QSC = 0.125f * 1.44269504089f;  // 1/sqrt(64) * log2(e)
  gemm_qkv<<<dim3(1536), 256, 0, stream>>>(
      q, k, v, WqT, WkT, WvT, bq, bk, bv, Qp, Kp, Vt, QSC);

  attn<<<dim3(512), 512, 0, stream>>>(Qp, Kp, Vt, At);

  gemm_out<<<dim3(512), 256, 0, stream>>>(At, WoT, bo, (float*)d_out);
}